// Round 9
// baseline (5658.033 us; speedup 1.0000x reference)
//
#include <hip/hip_runtime.h>
#include <hip/hip_bf16.h>
#include <math.h>

#define Bb   4
#define Hh   16
#define Tt   4096
#define Dd   64
#define Pp   128
#define MAXN 32
#define BHc  64   // B*H

typedef __bf16 bf16x8 __attribute__((ext_vector_type(8)));
typedef __bf16 bf16x4 __attribute__((ext_vector_type(4)));
typedef float  f32x4  __attribute__((ext_vector_type(4)));

// swizzled element index into a [row][128] __bf16 LDS tile
#define SW(row, col) (((row) * 128) + ((col) ^ (((row) & 15) << 3)))

// ---------------- precompute: cos/sin table for global positions ----------------
__global__ void k_postab(float* __restrict__ postab, unsigned* __restrict__ diag) {
    int idx = blockIdx.x * blockDim.x + threadIdx.x;
    if (idx < 3) diag[idx] = 0u;
    if (idx >= Tt * 16) return;
    int pos = idx >> 4, fi = idx & 15;
    float inv = (float)pow(10000.0, -(double)fi / 16.0);
    float ang = (float)pos * inv;
    postab[idx * 2 + 0] = cosf(ang);
    postab[idx * 2 + 1] = sinf(ang);
}

// ---------------- precompute: region starts + region cos/sin table ----------------
__global__ void k_prep(const int* __restrict__ regions, float* __restrict__ regtab,
                       int* __restrict__ starts) {
    int i = threadIdx.x;
    if (i < Bb * MAXN) {
        int b = i >> 5, n = (i & 31) + 1;
        const int* r = regions + b * Tt;
        int lo = 0, hi = Tt;
        while (lo < hi) { int mid = (lo + hi) >> 1; if (r[mid] < n) lo = mid + 1; else hi = mid; }
        starts[i] = (lo < Tt && r[lo] == n) ? lo : 0;
    }
    int j = i - Bb * MAXN;
    if (j >= 0 && j < 33 * 16) {
        int pos = j >> 4, fi = j & 15;
        float inv = (float)pow(10000.0, -(double)fi / 16.0);
        float ang = (float)pos * inv;
        regtab[j * 2 + 0] = cosf(ang);
        regtab[j * 2 + 1] = sinf(ang);
    }
}

// ---------------- dual-path instrumented kernel ----------------
// Path A (scalar, r7-proven) produces the output. Path B (full MFMA consumer,
// r8 structure but with dedicated persistent Q LDS) runs alongside; max
// discrepancies (m, O, l) are encoded into diag for k_combine to report.
__global__ __launch_bounds__(256) void k_attn(
    const float* __restrict__ q_in, const float* __restrict__ k_in,
    const float* __restrict__ v_in, const int* __restrict__ regions,
    const float* __restrict__ bias_same, const float* __restrict__ bias_diff,
    const float* __restrict__ postab, const float* __restrict__ regtab,
    const int* __restrict__ starts, float* __restrict__ pO,
    float* __restrict__ pML, unsigned* __restrict__ diag, int NS)
{
    const int bid   = blockIdx.x;
    const int chunk = bid % NS;
    const int bh    = bid / NS;
    const int b     = bh >> 4;
    const int h     = bh & 15;
    const int C     = Tt / NS;
    const int NTILE = C >> 6;
    const int c0    = chunk * C;

    const int tid = threadIdx.x;
    const int w  = tid >> 6;
    const int l  = tid & 63;
    const int cl = l & 15;
    const int g  = l >> 4;

    __shared__ __align__(16) __bf16 Qs[Pp * 128];    // q hi/lo, PERSISTENT (never overwritten)
    __shared__ __align__(16) __bf16 Ks[64 * 128];    // [t][k_hi|k_lo]
    __shared__ __align__(16) __bf16 Vs[64 * 128];    // [d][v_hi(t)|v_lo(t)] (transposed)
    __shared__ __align__(16) __bf16 Ps[Pp * 128];    // [p][p_hi(t)|p_lo(t)]
    __shared__ __align__(16) float rtab[33 * 16 * 2];
    __shared__ float mlA[Pp][2];
    __shared__ int regs_s[64];
    __shared__ int starts_s[MAXN];
    __shared__ unsigned dml[3];

    for (int j = tid; j < 33 * 16 * 2; j += 256) rtab[j] = regtab[j];
    if (tid < MAXN) starts_s[tid] = starts[b * MAXN + tid];
    if (tid < 3) dml[tid] = 0u;
    const float bs = bias_same[h];
    const float bd = bias_diff[h];
    __syncthreads();

    // ---- stage Q (rope + hi/lo) into the persistent Qs ----
    const float* Qbh = q_in + (size_t)bh * Pp * Dd;
#pragma unroll
    for (int it = 0; it < 8; ++it) {
        int f  = tid + 256 * it;
        int p  = f >> 4;
        int dq = (f & 15) << 2;
        float4 x = ((const float4*)Qbh)[f];
        int fi = (dq & 31) >> 1;
        float4 cs;
        if (dq < 32) {
            int gpos = starts_s[p >> 2];
            cs = *(const float4*)(postab + (size_t)(gpos * 16 + fi) * 2);
        } else {
            int ridx = (p >> 2) + 1;
            cs = *(const float4*)(&rtab[(ridx * 16 + fi) * 2]);
        }
        float v0 = x.x * cs.x - x.y * cs.y;
        float v1 = x.x * cs.y + x.y * cs.x;
        float v2 = x.z * cs.z - x.w * cs.w;
        float v3 = x.z * cs.w + x.w * cs.z;
        bf16x4 hh, ll;
        hh[0] = (__bf16)v0; ll[0] = (__bf16)(v0 - (float)hh[0]);
        hh[1] = (__bf16)v1; ll[1] = (__bf16)(v1 - (float)hh[1]);
        hh[2] = (__bf16)v2; ll[2] = (__bf16)(v2 - (float)hh[2]);
        hh[3] = (__bf16)v3; ll[3] = (__bf16)(v3 - (float)hh[3]);
        *(bf16x4*)(Qs + SW(p, dq))      = hh;
        *(bf16x4*)(Qs + SW(p, 64 + dq)) = ll;
    }
    __syncthreads();

    // ---- path A: reconstruct my q row from Qs bytes ----
    const int p = tid & 127;
    const int myridx = (p >> 2) + 1;
    float qf[64], o[64];
#pragma unroll
    for (int d4 = 0; d4 < 64; d4 += 4) {
        bf16x4 hh = *(const bf16x4*)(Qs + SW(p, d4));
        bf16x4 ll = *(const bf16x4*)(Qs + SW(p, 64 + d4));
        qf[d4 + 0] = (float)hh[0] + (float)ll[0];
        qf[d4 + 1] = (float)hh[1] + (float)ll[1];
        qf[d4 + 2] = (float)hh[2] + (float)ll[2];
        qf[d4 + 3] = (float)hh[3] + (float)ll[3];
    }
#pragma unroll
    for (int d = 0; d < 64; ++d) o[d] = 0.f;
    float mA = -INFINITY, lA = 0.f;

    // ---- path B: Q fragments (Qs is persistent -> re-loads would be harmless) ----
    bf16x8 qh[2][2], ql[2][2];
#pragma unroll
    for (int c = 0; c < 2; ++c) {
        int pr = w * 32 + c * 16 + cl;
#pragma unroll
        for (int ks = 0; ks < 2; ++ks) {
            qh[ks][c] = *(const bf16x8*)(Qs + SW(pr, ks * 32 + g * 8));
            ql[ks][c] = *(const bf16x8*)(Qs + SW(pr, 64 + ks * 32 + g * 8));
        }
    }

    float m0 = -INFINITY, m1 = -INFINITY, l0 = 0.f, l1 = 0.f;
    f32x4 Oacc[2][4];
#pragma unroll
    for (int i0 = 0; i0 < 2; ++i0)
#pragma unroll
        for (int i1 = 0; i1 < 4; ++i1) Oacc[i0][i1] = (f32x4)0.f;

    const float* Kbh = k_in + (size_t)bh * Tt * Dd;
    const float* Vbh = v_in + (size_t)bh * Tt * Dd;

    for (int tt = 0; tt < NTILE; ++tt) {
        const int t0 = c0 + tt * 64;
        __syncthreads();   // B1: previous tile fully consumed
        if (tid < 64) regs_s[tid] = regions[b * Tt + t0 + tid];

        // ---- stage K tile: rope + hi/lo ----
#pragma unroll
        for (int it = 0; it < 4; ++it) {
            int f   = tid + 256 * it;
            int row = f >> 4;
            int dq  = (f & 15) << 2;
            float4 x = ((const float4*)(Kbh + (size_t)t0 * Dd))[f];
            int fi = (dq & 31) >> 1;
            float4 cs;
            if (dq < 32) {
                cs = *(const float4*)(postab + (size_t)((t0 + row) * 16 + fi) * 2);
            } else {
                int rg = regions[b * Tt + t0 + row];
                cs = *(const float4*)(&rtab[(rg * 16 + fi) * 2]);
            }
            float v0 = x.x * cs.x - x.y * cs.y;
            float v1 = x.x * cs.y + x.y * cs.x;
            float v2 = x.z * cs.z - x.w * cs.w;
            float v3 = x.z * cs.w + x.w * cs.z;
            bf16x4 hh, ll;
            hh[0] = (__bf16)v0; ll[0] = (__bf16)(v0 - (float)hh[0]);
            hh[1] = (__bf16)v1; ll[1] = (__bf16)(v1 - (float)hh[1]);
            hh[2] = (__bf16)v2; ll[2] = (__bf16)(v2 - (float)hh[2]);
            hh[3] = (__bf16)v3; ll[3] = (__bf16)(v3 - (float)hh[3]);
            *(bf16x4*)(Ks + SW(row, dq))      = hh;
            *(bf16x4*)(Ks + SW(row, 64 + dq)) = ll;
        }

        // ---- stage V tile transposed to [d][t], hi/lo ----
        {
            int dcol = tid & 63;
            int tg   = (tid >> 6) * 8;
#pragma unroll
            for (int jj = 0; jj < 2; ++jj) {
                int tl = jj * 32 + tg;
                bf16x8 hh, ll;
#pragma unroll
                for (int r = 0; r < 8; ++r) {
                    float vv = Vbh[(size_t)(t0 + tl + r) * Dd + dcol];
                    __bf16 hu = (__bf16)vv;
                    hh[r] = hu;
                    ll[r] = (__bf16)(vv - (float)hu);
                }
                *(bf16x8*)(Vs + SW(dcol, tl))      = hh;
                *(bf16x8*)(Vs + SW(dcol, 64 + tl)) = ll;
            }
        }
        __syncthreads();   // B2: staging complete

        // ======== path B: QK^T MFMA ========
        f32x4 sacc[4][2];
#pragma unroll
        for (int mt = 0; mt < 4; ++mt) { sacc[mt][0] = (f32x4)0.f; sacc[mt][1] = (f32x4)0.f; }
        constexpr int AcolQ[6] = {0, 32, 64, 96, 0, 32};
#pragma unroll
        for (int s = 0; s < 6; ++s) {
            bf16x8 b0 = (s < 4) ? qh[s & 1][0] : ql[s & 1][0];
            bf16x8 b1 = (s < 4) ? qh[s & 1][1] : ql[s & 1][1];
#pragma unroll
            for (int mt = 0; mt < 4; ++mt) {
                int tr = mt * 16 + cl;
                bf16x8 ak = *(const bf16x8*)(Ks + SW(tr, AcolQ[s] + g * 8));
                sacc[mt][0] = __builtin_amdgcn_mfma_f32_16x16x32_bf16(ak, b0, sacc[mt][0], 0, 0, 0);
                sacc[mt][1] = __builtin_amdgcn_mfma_f32_16x16x32_bf16(ak, b1, sacc[mt][1], 0, 0, 0);
            }
        }

        float tmax0 = -INFINITY, tmax1 = -INFINITY;
        const int ridx0 = ((w * 32 + cl) >> 2) + 1;
        const int ridx1 = ((w * 32 + 16 + cl) >> 2) + 1;
#pragma unroll
        for (int mt = 0; mt < 4; ++mt) {
#pragma unroll
            for (int r = 0; r < 4; ++r) {
                int rg = regs_s[mt * 16 + g * 4 + r];
                float s0 = sacc[mt][0][r] * 0.125f + ((ridx0 == rg) ? bs : bd);
                float s1 = sacc[mt][1][r] * 0.125f + ((ridx1 == rg) ? bs : bd);
                sacc[mt][0][r] = s0; sacc[mt][1][r] = s1;
                tmax0 = fmaxf(tmax0, s0); tmax1 = fmaxf(tmax1, s1);
            }
        }
        tmax0 = fmaxf(tmax0, __shfl_xor(tmax0, 16, 64));
        tmax0 = fmaxf(tmax0, __shfl_xor(tmax0, 32, 64));
        tmax1 = fmaxf(tmax1, __shfl_xor(tmax1, 16, 64));
        tmax1 = fmaxf(tmax1, __shfl_xor(tmax1, 32, 64));
        float mn0 = fmaxf(m0, tmax0), mn1 = fmaxf(m1, tmax1);
        float sc0 = __expf(m0 - mn0), sc1 = __expf(m1 - mn1);

        float rs0 = 0.f, rs1 = 0.f;
#pragma unroll
        for (int mt = 0; mt < 4; ++mt) {
            bf16x4 ph0, pl0, ph1, pl1;
#pragma unroll
            for (int r = 0; r < 4; ++r) {
                float e0 = __expf(sacc[mt][0][r] - mn0);
                float e1 = __expf(sacc[mt][1][r] - mn1);
                rs0 += e0; rs1 += e1;
                __bf16 u0 = (__bf16)e0, u1 = (__bf16)e1;
                ph0[r] = u0; pl0[r] = (__bf16)(e0 - (float)u0);
                ph1[r] = u1; pl1[r] = (__bf16)(e1 - (float)u1);
            }
            int trow = mt * 16 + g * 4;
            int pa = w * 32 + cl;
            *(bf16x4*)(Ps + SW(pa, trow))      = ph0;
            *(bf16x4*)(Ps + SW(pa, 64 + trow)) = pl0;
            pa += 16;
            *(bf16x4*)(Ps + SW(pa, trow))      = ph1;
            *(bf16x4*)(Ps + SW(pa, 64 + trow)) = pl1;
        }
        rs0 += __shfl_xor(rs0, 16, 64); rs0 += __shfl_xor(rs0, 32, 64);
        rs1 += __shfl_xor(rs1, 16, 64); rs1 += __shfl_xor(rs1, 32, 64);
        l0 = l0 * sc0 + rs0; m0 = mn0;
        l1 = l1 * sc1 + rs1; m1 = mn1;

        __syncthreads();   // B3: P visible

#pragma unroll
        for (int r = 0; r < 4; ++r) {
            float f0 = __shfl(sc0, g * 4 + r, 64);
            float f1 = __shfl(sc1, g * 4 + r, 64);
#pragma unroll
            for (int nt = 0; nt < 4; ++nt) {
                Oacc[0][nt][r] *= f0;
                Oacc[1][nt][r] *= f1;
            }
        }

        constexpr int AcolP[6] = {0, 32, 0, 32, 64, 96};
        constexpr int BcolV[6] = {0, 32, 64, 96, 0, 32};
#pragma unroll
        for (int s = 0; s < 6; ++s) {
            bf16x8 ap0, ap1;
            {
                int pp = w * 32 + cl;
                ap0 = *(const bf16x8*)(Ps + SW(pp, AcolP[s] + g * 8));
                ap1 = *(const bf16x8*)(Ps + SW(pp + 16, AcolP[s] + g * 8));
            }
#pragma unroll
            for (int nt = 0; nt < 4; ++nt) {
                int d = nt * 16 + cl;
                bf16x8 bv = *(const bf16x8*)(Vs + SW(d, BcolV[s] + g * 8));
                Oacc[0][nt] = __builtin_amdgcn_mfma_f32_16x16x32_bf16(ap0, bv, Oacc[0][nt], 0, 0, 0);
                Oacc[1][nt] = __builtin_amdgcn_mfma_f32_16x16x32_bf16(ap1, bv, Oacc[1][nt], 0, 0, 0);
            }
        }

        // ======== path A: trusted scalar consumer (same staged bytes) ========
        if (tid < 128) {
            for (int j = 0; j < 64; ++j) {
                float s0 = 0.f, s1 = 0.f, s2 = 0.f, s3 = 0.f;
#pragma unroll
                for (int d4 = 0; d4 < 64; d4 += 4) {
                    bf16x4 kh = *(const bf16x4*)(Ks + SW(j, d4));
                    bf16x4 kl = *(const bf16x4*)(Ks + SW(j, 64 + d4));
                    s0 += ((float)kh[0] + (float)kl[0]) * qf[d4 + 0];
                    s1 += ((float)kh[1] + (float)kl[1]) * qf[d4 + 1];
                    s2 += ((float)kh[2] + (float)kl[2]) * qf[d4 + 2];
                    s3 += ((float)kh[3] + (float)kl[3]) * qf[d4 + 3];
                }
                float s = ((s0 + s1) + (s2 + s3)) * 0.125f + ((myridx == regs_s[j]) ? bs : bd);
                if (s <= mA) {
                    float e = __expf(s - mA);
                    lA += e;
#pragma unroll
                    for (int d = 0; d < 64; ++d)
                        o[d] += e * ((float)Vs[SW(d, j)] + (float)Vs[SW(d, 64 + j)]);
                } else {
                    float cc = __expf(mA - s);
                    mA = s;
                    lA = lA * cc + 1.f;
#pragma unroll
                    for (int d = 0; d < 64; ++d)
                        o[d] = o[d] * cc + ((float)Vs[SW(d, j)] + (float)Vs[SW(d, 64 + j)]);
                }
            }
        }
    }

    // ---- path A writes output partials + its results for comparison ----
    __syncthreads();
    float* oA = (float*)Qs;   // Qs no longer needed
    if (tid < 128) {
        size_t obase = (size_t)(bh * NS + chunk) * Pp * Dd + (size_t)p * Dd;
#pragma unroll
        for (int d = 0; d < 64; ++d) { pO[obase + d] = o[d]; oA[p * 64 + d] = o[d]; }
        mlA[p][0] = mA; mlA[p][1] = lA;
        size_t mlb = (size_t)(bh * NS + chunk) * Pp;
        *(float2*)(pML + (mlb + p) * 2) = make_float2(mA, lA);
    }
    __syncthreads();

    // ---- compare path B vs path A ----
    {
        float dM = 0.f, dO = 0.f, dL = 0.f;
        int p0 = w * 32 + cl;
        dM = fmaxf(fabsf(m0 - mlA[p0][0]), fabsf(m1 - mlA[p0 + 16][0]));
        dL = fmaxf(fabsf(l0 - mlA[p0][1]) / fmaxf(1e-6f, fabsf(mlA[p0][1])),
                   fabsf(l1 - mlA[p0 + 16][1]) / fmaxf(1e-6f, fabsf(mlA[p0 + 16][1])));
#pragma unroll
        for (int mtp = 0; mtp < 2; ++mtp)
#pragma unroll
            for (int nt = 0; nt < 4; ++nt)
#pragma unroll
                for (int r = 0; r < 4; ++r) {
                    int pb = w * 32 + mtp * 16 + g * 4 + r;
                    int d  = nt * 16 + cl;
                    float ref = oA[pb * 64 + d];
                    float dd  = fabsf(Oacc[mtp][nt][r] - ref) / fmaxf(1.f, fabsf(ref));
                    dO = fmaxf(dO, dd);
                }
        atomicMax(&dml[0], __float_as_uint(dM));
        atomicMax(&dml[1], __float_as_uint(dO));
        atomicMax(&dml[2], __float_as_uint(dL));
    }
    __syncthreads();
    if (tid < 3) atomicMax(&diag[tid], dml[tid]);
}

// ---------------- combine partials across T-chunks ----------------
__global__ void k_combine(const float* __restrict__ pO, const float* __restrict__ pML,
                          float* __restrict__ out, const unsigned* __restrict__ diag, int NS) {
    int bh = blockIdx.x >> 2;
    int pq = blockIdx.x & 3;
    int d  = threadIdx.x & 63;
    int ps = threadIdx.x >> 6;
    for (int pp = 0; pp < 8; ++pp) {
        int p = pq * 32 + pp * 4 + ps;
        float M = -INFINITY;
        float mv[8], lv[8];
        for (int c = 0; c < NS; ++c) {
            float2 ml = *(const float2*)(pML + ((size_t)(bh * NS + c) * Pp + p) * 2);
            mv[c] = ml.x; lv[c] = ml.y;
            M = fmaxf(M, ml.x);
        }
        float L = 0.f, o = 0.f;
        for (int c = 0; c < NS; ++c) {
            float wgt = __expf(mv[c] - M);
            L += wgt * lv[c];
            o += wgt * pO[((size_t)(bh * NS + c) * Pp + p) * Dd + d];
        }
        out[((size_t)bh * Pp + p) * Dd + d] = o / L;
    }
    // encode MFMA-vs-scalar discrepancies into out[0]:
    //   dM -> [0.01, 0.3];  dO -> [1, 301];  dL -> [400, 700]
    if (blockIdx.x == 0 && threadIdx.x == 0) {
        float dM = __uint_as_float(diag[0]);
        float dO = __uint_as_float(diag[1]);
        float dL = __uint_as_float(diag[2]);
        float enc = 0.f;
        if (dM > 2e-3f) enc += 0.01f + fminf(dM, 0.29f);
        if (dO > 2e-3f) enc += 1.f + fminf(dO * 30.f, 300.f);
        if (dL > 2e-3f) enc += 400.f + fminf(dL * 100.f, 300.f);
        out[0] += enc;
    }
}

// ---------------- launcher ----------------
extern "C" void kernel_launch(void* const* d_in, const int* in_sizes, int n_in,
                              void* d_out, int out_size, void* d_ws, size_t ws_size,
                              hipStream_t stream) {
    const float* q         = (const float*)d_in[0];
    const float* k         = (const float*)d_in[1];
    const float* v         = (const float*)d_in[2];
    const int*   regions   = (const int*)d_in[3];
    const float* bias_same = (const float*)d_in[7];
    const float* bias_diff = (const float*)d_in[8];

    float* ws     = (float*)d_ws;
    float* postab = ws;                              // 4096*16*2 floats
    float* regtab = postab + Tt * 16 * 2;            // 33*16*2 floats
    int*   starts = (int*)(regtab + 33 * 16 * 2);    // 128 ints
    unsigned* diag = (unsigned*)(starts + 128);      // 64 slots (use [0..2])
    float* pbase  = (float*)(diag + 64);
    size_t fixed_b = (size_t)((char*)pbase - (char*)ws);

    int NS = 8;
    while (NS > 1 && fixed_b + (size_t)BHc * NS * Pp * (Dd + 2) * 4 > ws_size) NS >>= 1;
    float* pO  = pbase;
    float* pML = pO + (size_t)BHc * NS * Pp * Dd;

    k_postab<<<dim3(Tt * 16 / 256), dim3(256), 0, stream>>>(postab, diag);
    k_prep<<<dim3(1), dim3(704), 0, stream>>>(regions, regtab, starts);
    k_attn<<<dim3(BHc * NS), dim3(256), 0, stream>>>(q, k, v, regions, bias_same, bias_diff,
                                                     postab, regtab, starts, pO, pML, diag, NS);
    k_combine<<<dim3(BHc * 4), dim3(256), 0, stream>>>(pO, pML, (float*)d_out, diag, NS);
}

// Round 11
// 5637.542 us; speedup vs baseline: 1.0036x; 1.0036x over previous
//
#include <hip/hip_runtime.h>
#include <hip/hip_bf16.h>
#include <math.h>

#define Bb   4
#define Hh   16
#define Tt   4096
#define Dd   64
#define Pp   128
#define MAXN 32
#define BHc  64   // B*H

typedef __bf16 bf16x8 __attribute__((ext_vector_type(8)));
typedef __bf16 bf16x4 __attribute__((ext_vector_type(4)));
typedef float  f32x4  __attribute__((ext_vector_type(4)));

// swizzled element index into a [row][128] __bf16 LDS tile
#define SW(row, col) (((row) * 128) + ((col) ^ (((row) & 15) << 3)))

// ---------------- precompute: cos/sin table for global positions ----------------
__global__ void k_postab(float* __restrict__ postab, unsigned* __restrict__ diag) {
    int idx = blockIdx.x * blockDim.x + threadIdx.x;
    if (idx < 3) diag[idx] = 0u;
    if (idx >= Tt * 16) return;
    int pos = idx >> 4, fi = idx & 15;
    float inv = (float)pow(10000.0, -(double)fi / 16.0);
    float ang = (float)pos * inv;
    postab[idx * 2 + 0] = cosf(ang);
    postab[idx * 2 + 1] = sinf(ang);
}

// ---------------- precompute: region starts + region cos/sin table ----------------
__global__ void k_prep(const int* __restrict__ regions, float* __restrict__ regtab,
                       int* __restrict__ starts) {
    int i = threadIdx.x;
    if (i < Bb * MAXN) {
        int b = i >> 5, n = (i & 31) + 1;
        const int* r = regions + b * Tt;
        int lo = 0, hi = Tt;
        while (lo < hi) { int mid = (lo + hi) >> 1; if (r[mid] < n) lo = mid + 1; else hi = mid; }
        starts[i] = (lo < Tt && r[lo] == n) ? lo : 0;
    }
    int j = i - Bb * MAXN;
    if (j >= 0 && j < 33 * 16) {
        int pos = j >> 4, fi = j & 15;
        float inv = (float)pow(10000.0, -(double)fi / 16.0);
        float ang = (float)pos * inv;
        regtab[j * 2 + 0] = cosf(ang);
        regtab[j * 2 + 1] = sinf(ang);
    }
}

// ---------------- dual-path kernel: path B (MFMA) OUTPUT, path A comparison ----------------
__global__ __launch_bounds__(256) void k_attn(
    const float* __restrict__ q_in, const float* __restrict__ k_in,
    const float* __restrict__ v_in, const int* __restrict__ regions,
    const float* __restrict__ bias_same, const float* __restrict__ bias_diff,
    const float* __restrict__ postab, const float* __restrict__ regtab,
    const int* __restrict__ starts, float* __restrict__ pO,
    float* __restrict__ pML, unsigned* __restrict__ diag, int NS)
{
    const int bid   = blockIdx.x;
    const int chunk = bid % NS;
    const int bh    = bid / NS;
    const int b     = bh >> 4;
    const int h     = bh & 15;
    const int C     = Tt / NS;
    const int NTILE = C >> 6;
    const int c0    = chunk * C;

    const int tid = threadIdx.x;
    const int w  = tid >> 6;
    const int l  = tid & 63;
    const int cl = l & 15;
    const int g  = l >> 4;

    __shared__ __align__(16) __bf16 Qs[Pp * 128];    // q hi/lo, PERSISTENT during loop
    __shared__ __align__(16) __bf16 Ks[64 * 128];
    __shared__ __align__(16) __bf16 Vs[64 * 128];
    __shared__ __align__(16) __bf16 Ps[Pp * 128];
    __shared__ __align__(16) float rtab[33 * 16 * 2];
    __shared__ float mlA[Pp][2];
    __shared__ int regs_s[64];
    __shared__ int starts_s[MAXN];
    __shared__ unsigned dml[3];

    for (int j = tid; j < 33 * 16 * 2; j += 256) rtab[j] = regtab[j];
    if (tid < MAXN) starts_s[tid] = starts[b * MAXN + tid];
    if (tid < 3) dml[tid] = 0u;
    const float bs = bias_same[h];
    const float bd = bias_diff[h];
    __syncthreads();

    // ---- stage Q (rope + hi/lo) into persistent Qs ----
    const float* Qbh = q_in + (size_t)bh * Pp * Dd;
#pragma unroll
    for (int it = 0; it < 8; ++it) {
        int f  = tid + 256 * it;
        int p  = f >> 4;
        int dq = (f & 15) << 2;
        float4 x = ((const float4*)Qbh)[f];
        int fi = (dq & 31) >> 1;
        float4 cs;
        if (dq < 32) {
            int gpos = starts_s[p >> 2];
            cs = *(const float4*)(postab + (size_t)(gpos * 16 + fi) * 2);
        } else {
            int ridx = (p >> 2) + 1;
            cs = *(const float4*)(&rtab[(ridx * 16 + fi) * 2]);
        }
        float v0 = x.x * cs.x - x.y * cs.y;
        float v1 = x.x * cs.y + x.y * cs.x;
        float v2 = x.z * cs.z - x.w * cs.w;
        float v3 = x.z * cs.w + x.w * cs.z;
        bf16x4 hh, ll;
        hh[0] = (__bf16)v0; ll[0] = (__bf16)(v0 - (float)hh[0]);
        hh[1] = (__bf16)v1; ll[1] = (__bf16)(v1 - (float)hh[1]);
        hh[2] = (__bf16)v2; ll[2] = (__bf16)(v2 - (float)hh[2]);
        hh[3] = (__bf16)v3; ll[3] = (__bf16)(v3 - (float)hh[3]);
        *(bf16x4*)(Qs + SW(p, dq))      = hh;
        *(bf16x4*)(Qs + SW(p, 64 + dq)) = ll;
    }
    __syncthreads();

    // ---- path A: reconstruct my q row from Qs bytes ----
    const int p = tid & 127;
    const int myridx = (p >> 2) + 1;
    float qf[64], o[64];
#pragma unroll
    for (int d4 = 0; d4 < 64; d4 += 4) {
        bf16x4 hh = *(const bf16x4*)(Qs + SW(p, d4));
        bf16x4 ll = *(const bf16x4*)(Qs + SW(p, 64 + d4));
        qf[d4 + 0] = (float)hh[0] + (float)ll[0];
        qf[d4 + 1] = (float)hh[1] + (float)ll[1];
        qf[d4 + 2] = (float)hh[2] + (float)ll[2];
        qf[d4 + 3] = (float)hh[3] + (float)ll[3];
    }
#pragma unroll
    for (int d = 0; d < 64; ++d) o[d] = 0.f;
    float mA = -INFINITY, lA = 0.f;

    // ---- path B: Q fragments from LDS (r9-validated source) ----
    bf16x8 qh[2][2], ql[2][2];
#pragma unroll
    for (int c = 0; c < 2; ++c) {
        int pr = w * 32 + c * 16 + cl;
#pragma unroll
        for (int ks = 0; ks < 2; ++ks) {
            qh[ks][c] = *(const bf16x8*)(Qs + SW(pr, ks * 32 + g * 8));
            ql[ks][c] = *(const bf16x8*)(Qs + SW(pr, 64 + ks * 32 + g * 8));
        }
    }

    float m0 = -INFINITY, m1 = -INFINITY, l0 = 0.f, l1 = 0.f;
    f32x4 Oacc[2][4];
#pragma unroll
    for (int i0 = 0; i0 < 2; ++i0)
#pragma unroll
        for (int i1 = 0; i1 < 4; ++i1) Oacc[i0][i1] = (f32x4)0.f;

    const float* Kbh = k_in + (size_t)bh * Tt * Dd;
    const float* Vbh = v_in + (size_t)bh * Tt * Dd;

    for (int tt = 0; tt < NTILE; ++tt) {
        const int t0 = c0 + tt * 64;
        __syncthreads();
        if (tid < 64) regs_s[tid] = regions[b * Tt + t0 + tid];

        // ---- stage K tile: rope + hi/lo ----
#pragma unroll
        for (int it = 0; it < 4; ++it) {
            int f   = tid + 256 * it;
            int row = f >> 4;
            int dq  = (f & 15) << 2;
            float4 x = ((const float4*)(Kbh + (size_t)t0 * Dd))[f];
            int fi = (dq & 31) >> 1;
            float4 cs;
            if (dq < 32) {
                cs = *(const float4*)(postab + (size_t)((t0 + row) * 16 + fi) * 2);
            } else {
                int rg = regions[b * Tt + t0 + row];
                cs = *(const float4*)(&rtab[(rg * 16 + fi) * 2]);
            }
            float v0 = x.x * cs.x - x.y * cs.y;
            float v1 = x.x * cs.y + x.y * cs.x;
            float v2 = x.z * cs.z - x.w * cs.w;
            float v3 = x.z * cs.w + x.w * cs.z;
            bf16x4 hh, ll;
            hh[0] = (__bf16)v0; ll[0] = (__bf16)(v0 - (float)hh[0]);
            hh[1] = (__bf16)v1; ll[1] = (__bf16)(v1 - (float)hh[1]);
            hh[2] = (__bf16)v2; ll[2] = (__bf16)(v2 - (float)hh[2]);
            hh[3] = (__bf16)v3; ll[3] = (__bf16)(v3 - (float)hh[3]);
            *(bf16x4*)(Ks + SW(row, dq))      = hh;
            *(bf16x4*)(Ks + SW(row, 64 + dq)) = ll;
        }

        // ---- stage V tile transposed to [d][t], hi/lo ----
        {
            int dcol = tid & 63;
            int tg   = (tid >> 6) * 8;
#pragma unroll
            for (int jj = 0; jj < 2; ++jj) {
                int tl = jj * 32 + tg;
                bf16x8 hh, ll;
#pragma unroll
                for (int r = 0; r < 8; ++r) {
                    float vv = Vbh[(size_t)(t0 + tl + r) * Dd + dcol];
                    __bf16 hu = (__bf16)vv;
                    hh[r] = hu;
                    ll[r] = (__bf16)(vv - (float)hu);
                }
                *(bf16x8*)(Vs + SW(dcol, tl))      = hh;
                *(bf16x8*)(Vs + SW(dcol, 64 + tl)) = ll;
            }
        }
        __syncthreads();

        // ======== path B: QK^T MFMA ========
        f32x4 sacc[4][2];
#pragma unroll
        for (int mt = 0; mt < 4; ++mt) { sacc[mt][0] = (f32x4)0.f; sacc[mt][1] = (f32x4)0.f; }
        constexpr int AcolQ[6] = {0, 32, 64, 96, 0, 32};
#pragma unroll
        for (int s = 0; s < 6; ++s) {
            bf16x8 b0 = (s < 4) ? qh[s & 1][0] : ql[s & 1][0];
            bf16x8 b1 = (s < 4) ? qh[s & 1][1] : ql[s & 1][1];
#pragma unroll
            for (int mt = 0; mt < 4; ++mt) {
                int tr = mt * 16 + cl;
                bf16x8 ak = *(const bf16x8*)(Ks + SW(tr, AcolQ[s] + g * 8));
                sacc[mt][0] = __builtin_amdgcn_mfma_f32_16x16x32_bf16(ak, b0, sacc[mt][0], 0, 0, 0);
                sacc[mt][1] = __builtin_amdgcn_mfma_f32_16x16x32_bf16(ak, b1, sacc[mt][1], 0, 0, 0);
            }
        }

        float tmax0 = -INFINITY, tmax1 = -INFINITY;
        const int ridx0 = ((w * 32 + cl) >> 2) + 1;
        const int ridx1 = ((w * 32 + 16 + cl) >> 2) + 1;
#pragma unroll
        for (int mt = 0; mt < 4; ++mt) {
#pragma unroll
            for (int r = 0; r < 4; ++r) {
                int rg = regs_s[mt * 16 + g * 4 + r];
                float s0 = sacc[mt][0][r] * 0.125f + ((ridx0 == rg) ? bs : bd);
                float s1 = sacc[mt][1][r] * 0.125f + ((ridx1 == rg) ? bs : bd);
                sacc[mt][0][r] = s0; sacc[mt][1][r] = s1;
                tmax0 = fmaxf(tmax0, s0); tmax1 = fmaxf(tmax1, s1);
            }
        }
        tmax0 = fmaxf(tmax0, __shfl_xor(tmax0, 16, 64));
        tmax0 = fmaxf(tmax0, __shfl_xor(tmax0, 32, 64));
        tmax1 = fmaxf(tmax1, __shfl_xor(tmax1, 16, 64));
        tmax1 = fmaxf(tmax1, __shfl_xor(tmax1, 32, 64));
        float mn0 = fmaxf(m0, tmax0), mn1 = fmaxf(m1, tmax1);
        float sc0 = __expf(m0 - mn0), sc1 = __expf(m1 - mn1);

        float rs0 = 0.f, rs1 = 0.f;
#pragma unroll
        for (int mt = 0; mt < 4; ++mt) {
            bf16x4 ph0, pl0, ph1, pl1;
#pragma unroll
            for (int r = 0; r < 4; ++r) {
                float e0 = __expf(sacc[mt][0][r] - mn0);
                float e1 = __expf(sacc[mt][1][r] - mn1);
                rs0 += e0; rs1 += e1;
                __bf16 u0 = (__bf16)e0, u1 = (__bf16)e1;
                ph0[r] = u0; pl0[r] = (__bf16)(e0 - (float)u0);
                ph1[r] = u1; pl1[r] = (__bf16)(e1 - (float)u1);
            }
            int trow = mt * 16 + g * 4;
            int pa = w * 32 + cl;
            *(bf16x4*)(Ps + SW(pa, trow))      = ph0;
            *(bf16x4*)(Ps + SW(pa, 64 + trow)) = pl0;
            pa += 16;
            *(bf16x4*)(Ps + SW(pa, trow))      = ph1;
            *(bf16x4*)(Ps + SW(pa, 64 + trow)) = pl1;
        }
        rs0 += __shfl_xor(rs0, 16, 64); rs0 += __shfl_xor(rs0, 32, 64);
        rs1 += __shfl_xor(rs1, 16, 64); rs1 += __shfl_xor(rs1, 32, 64);
        l0 = l0 * sc0 + rs0; m0 = mn0;
        l1 = l1 * sc1 + rs1; m1 = mn1;

        __syncthreads();   // P visible

#pragma unroll
        for (int r = 0; r < 4; ++r) {
            float f0 = __shfl(sc0, g * 4 + r, 64);
            float f1 = __shfl(sc1, g * 4 + r, 64);
#pragma unroll
            for (int nt = 0; nt < 4; ++nt) {
                Oacc[0][nt][r] *= f0;
                Oacc[1][nt][r] *= f1;
            }
        }

        constexpr int AcolP[6] = {0, 32, 0, 32, 64, 96};
        constexpr int BcolV[6] = {0, 32, 64, 96, 0, 32};
#pragma unroll
        for (int s = 0; s < 6; ++s) {
            bf16x8 ap0, ap1;
            {
                int pp = w * 32 + cl;
                ap0 = *(const bf16x8*)(Ps + SW(pp, AcolP[s] + g * 8));
                ap1 = *(const bf16x8*)(Ps + SW(pp + 16, AcolP[s] + g * 8));
            }
#pragma unroll
            for (int nt = 0; nt < 4; ++nt) {
                int d = nt * 16 + cl;
                bf16x8 bv = *(const bf16x8*)(Vs + SW(d, BcolV[s] + g * 8));
                Oacc[0][nt] = __builtin_amdgcn_mfma_f32_16x16x32_bf16(ap0, bv, Oacc[0][nt], 0, 0, 0);
                Oacc[1][nt] = __builtin_amdgcn_mfma_f32_16x16x32_bf16(ap1, bv, Oacc[1][nt], 0, 0, 0);
            }
        }

        // ======== path A: trusted scalar consumer (same staged bytes) ========
        if (tid < 128) {
            for (int j = 0; j < 64; ++j) {
                float s0 = 0.f, s1 = 0.f, s2 = 0.f, s3 = 0.f;
#pragma unroll
                for (int d4 = 0; d4 < 64; d4 += 4) {
                    bf16x4 kh = *(const bf16x4*)(Ks + SW(j, d4));
                    bf16x4 kl = *(const bf16x4*)(Ks + SW(j, 64 + d4));
                    s0 += ((float)kh[0] + (float)kl[0]) * qf[d4 + 0];
                    s1 += ((float)kh[1] + (float)kl[1]) * qf[d4 + 1];
                    s2 += ((float)kh[2] + (float)kl[2]) * qf[d4 + 2];
                    s3 += ((float)kh[3] + (float)kl[3]) * qf[d4 + 3];
                }
                float s = ((s0 + s1) + (s2 + s3)) * 0.125f + ((myridx == regs_s[j]) ? bs : bd);
                if (s <= mA) {
                    float e = __expf(s - mA);
                    lA += e;
#pragma unroll
                    for (int d = 0; d < 64; ++d)
                        o[d] += e * ((float)Vs[SW(d, j)] + (float)Vs[SW(d, 64 + j)]);
                } else {
                    float cc = __expf(mA - s);
                    mA = s;
                    lA = lA * cc + 1.f;
#pragma unroll
                    for (int d = 0; d < 64; ++d)
                        o[d] = o[d] * cc + ((float)Vs[SW(d, j)] + (float)Vs[SW(d, 64 + j)]);
                }
            }
        }
    }

    // ---- path B writes the output partials ----
    size_t obase = (size_t)(bh * NS + chunk) * Pp * Dd;
#pragma unroll
    for (int mtp = 0; mtp < 2; ++mtp)
#pragma unroll
        for (int nt = 0; nt < 4; ++nt)
#pragma unroll
            for (int r = 0; r < 4; ++r) {
                int pb = w * 32 + mtp * 16 + g * 4 + r;
                int d  = nt * 16 + cl;
                pO[obase + pb * 64 + d] = Oacc[mtp][nt][r];
            }
    if (g == 0) {
        size_t mlb = (size_t)(bh * NS + chunk) * Pp;
        int p0 = w * 32 + cl;
        *(float2*)(pML + (mlb + p0) * 2)      = make_float2(m0, l0);
        *(float2*)(pML + (mlb + p0 + 16) * 2) = make_float2(m1, l1);
    }

    // ---- path A results to LDS for comparison ----
    __syncthreads();
    float* oA = (float*)Qs;   // Qs no longer needed
    if (tid < 128) {
#pragma unroll
        for (int d = 0; d < 64; ++d) oA[p * 64 + d] = o[d];
        mlA[p][0] = mA; mlA[p][1] = lA;
    }
    __syncthreads();

    // ---- compare path B vs path A (tight) ----
    {
        float dM = 0.f, dO = 0.f, dL = 0.f;
        int p0 = w * 32 + cl;
        dM = fmaxf(fabsf(m0 - mlA[p0][0]), fabsf(m1 - mlA[p0 + 16][0]));
        dL = fmaxf(fabsf(l0 - mlA[p0][1]) / fmaxf(1e-6f, fabsf(mlA[p0][1])),
                   fabsf(l1 - mlA[p0 + 16][1]) / fmaxf(1e-6f, fabsf(mlA[p0 + 16][1])));
#pragma unroll
        for (int mtp = 0; mtp < 2; ++mtp)
#pragma unroll
            for (int nt = 0; nt < 4; ++nt)
#pragma unroll
                for (int r = 0; r < 4; ++r) {
                    int pb = w * 32 + mtp * 16 + g * 4 + r;
                    int d  = nt * 16 + cl;
                    float ref = oA[pb * 64 + d];
                    float dd  = fabsf(Oacc[mtp][nt][r] - ref) / fmaxf(1.f, fabsf(ref));
                    dO = fmaxf(dO, dd);
                }
        atomicMax(&dml[0], __float_as_uint(dM));
        atomicMax(&dml[1], __float_as_uint(dO));
        atomicMax(&dml[2], __float_as_uint(dL));
    }
    __syncthreads();
    if (tid < 3) atomicMax(&diag[tid], dml[tid]);
}

// ---------------- combine partials across T-chunks ----------------
__global__ void k_combine(const float* __restrict__ pO, const float* __restrict__ pML,
                          float* __restrict__ out, const unsigned* __restrict__ diag, int NS) {
    int bh = blockIdx.x >> 2;
    int pq = blockIdx.x & 3;
    int d  = threadIdx.x & 63;
    int ps = threadIdx.x >> 6;
    for (int pp = 0; pp < 8; ++pp) {
        int p = pq * 32 + pp * 4 + ps;
        float M = -INFINITY;
        float mv[8], lv[8];
        for (int c = 0; c < NS; ++c) {
            float2 ml = *(const float2*)(pML + ((size_t)(bh * NS + c) * Pp + p) * 2);
            mv[c] = ml.x; lv[c] = ml.y;
            M = fmaxf(M, ml.x);
        }
        float L = 0.f, o = 0.f;
        for (int c = 0; c < NS; ++c) {
            float wgt = __expf(mv[c] - M);
            L += wgt * lv[c];
            o += wgt * pO[((size_t)(bh * NS + c) * Pp + p) * Dd + d];
        }
        out[((size_t)bh * Pp + p) * Dd + d] = o / L;
    }
    // tight diagnostic bands: dM -> [7,14]; dO -> [70,140]; dL -> [700,1400]
    if (blockIdx.x == 0 && threadIdx.x == 0) {
        float dM = __uint_as_float(diag[0]);
        float dO = __uint_as_float(diag[1]);
        float dL = __uint_as_float(diag[2]);
        float enc = 0.f;
        if (dM > 2e-4f) enc += 7.f   + fminf(dM * 300.f, 7.f);
        if (dO > 5e-4f) enc += 70.f  + fminf(dO * 3000.f, 70.f);
        if (dL > 5e-4f) enc += 700.f + fminf(dL * 30000.f, 700.f);
        out[0] += enc;
    }
}

// ---------------- launcher ----------------
extern "C" void kernel_launch(void* const* d_in, const int* in_sizes, int n_in,
                              void* d_out, int out_size, void* d_ws, size_t ws_size,
                              hipStream_t stream) {
    const float* q         = (const float*)d_in[0];
    const float* k         = (const float*)d_in[1];
    const float* v         = (const float*)d_in[2];
    const int*   regions   = (const int*)d_in[3];
    const float* bias_same = (const float*)d_in[7];
    const float* bias_diff = (const float*)d_in[8];

    float* ws     = (float*)d_ws;
    float* postab = ws;
    float* regtab = postab + Tt * 16 * 2;
    int*   starts = (int*)(regtab + 33 * 16 * 2);
    unsigned* diag = (unsigned*)(starts + 128);
    float* pbase  = (float*)(diag + 64);
    size_t fixed_b = (size_t)((char*)pbase - (char*)ws);

    int NS = 8;
    while (NS > 1 && fixed_b + (size_t)BHc * NS * Pp * (Dd + 2) * 4 > ws_size) NS >>= 1;
    float* pO  = pbase;
    float* pML = pO + (size_t)BHc * NS * Pp * Dd;

    k_postab<<<dim3(Tt * 16 / 256), dim3(256), 0, stream>>>(postab, diag);
    k_prep<<<dim3(1), dim3(704), 0, stream>>>(regions, regtab, starts);
    k_attn<<<dim3(BHc * NS), dim3(256), 0, stream>>>(q, k, v, regions, bias_same, bias_diff,
                                                     postab, regtab, starts, pO, pML, diag, NS);
    k_combine<<<dim3(BHc * 4), dim3(256), 0, stream>>>(pO, pML, (float*)d_out, diag, NS);
}

// Round 12
// 138.410 us; speedup vs baseline: 40.8787x; 40.7306x over previous
//
#include <hip/hip_runtime.h>
#include <hip/hip_bf16.h>
#include <math.h>

#define Bb   4
#define Hh   16
#define Tt   4096
#define Dd   64
#define Pp   128
#define MAXN 32
#define BHc  64   // B*H

typedef __bf16 bf16x8 __attribute__((ext_vector_type(8)));
typedef __bf16 bf16x4 __attribute__((ext_vector_type(4)));
typedef float  f32x4  __attribute__((ext_vector_type(4)));

// swizzled element index into a [row][128] __bf16 LDS tile
#define SW(row, col) (((row) * 128) + ((col) ^ (((row) & 15) << 3)))

// ---------------- precompute: cos/sin table for global positions ----------------
__global__ void k_postab(float* __restrict__ postab) {
    int idx = blockIdx.x * blockDim.x + threadIdx.x;
    if (idx >= Tt * 16) return;
    int pos = idx >> 4, fi = idx & 15;
    float inv = (float)pow(10000.0, -(double)fi / 16.0);
    float ang = (float)pos * inv;
    postab[idx * 2 + 0] = cosf(ang);
    postab[idx * 2 + 1] = sinf(ang);
}

// ---------------- precompute: region starts + region cos/sin table ----------------
__global__ void k_prep(const int* __restrict__ regions, float* __restrict__ regtab,
                       int* __restrict__ starts) {
    int i = threadIdx.x;
    if (i < Bb * MAXN) {
        int b = i >> 5, n = (i & 31) + 1;
        const int* r = regions + b * Tt;
        int lo = 0, hi = Tt;
        while (lo < hi) { int mid = (lo + hi) >> 1; if (r[mid] < n) lo = mid + 1; else hi = mid; }
        starts[i] = (lo < Tt && r[lo] == n) ? lo : 0;
    }
    int j = i - Bb * MAXN;
    if (j >= 0 && j < 33 * 16) {
        int pos = j >> 4, fi = j & 15;
        float inv = (float)pow(10000.0, -(double)fi / 16.0);
        float ang = (float)pos * inv;
        regtab[j * 2 + 0] = cosf(ang);
        regtab[j * 2 + 1] = sinf(ang);
    }
}

// ---------------- main flash-attention kernel (r11-validated path B, stripped) ----------------
// Q staged once into PERSISTENT LDS (never overwritten -> no remat hazard);
// K/V/P in swizzled __bf16 hi/lo LDS tiles; hi/lo 3-term MFMA (~f32 precision).
__global__ __launch_bounds__(256) void k_attn(
    const float* __restrict__ q_in, const float* __restrict__ k_in,
    const float* __restrict__ v_in, const int* __restrict__ regions,
    const float* __restrict__ bias_same, const float* __restrict__ bias_diff,
    const float* __restrict__ postab, const float* __restrict__ regtab,
    const int* __restrict__ starts, float* __restrict__ pO,
    float* __restrict__ pML, int NS)
{
    const int bid   = blockIdx.x;
    const int chunk = bid % NS;
    const int bh    = bid / NS;
    const int b     = bh >> 4;
    const int h     = bh & 15;
    const int C     = Tt / NS;
    const int NTILE = C >> 6;
    const int c0    = chunk * C;

    const int tid = threadIdx.x;
    const int w  = tid >> 6;
    const int l  = tid & 63;
    const int cl = l & 15;
    const int g  = l >> 4;

    __shared__ __align__(16) __bf16 Qs[Pp * 128];    // q hi/lo, PERSISTENT
    __shared__ __align__(16) __bf16 Ks[64 * 128];
    __shared__ __align__(16) __bf16 Vs[64 * 128];
    __shared__ __align__(16) __bf16 Ps[Pp * 128];
    __shared__ __align__(16) float rtab[33 * 16 * 2];
    __shared__ int regs_s[64];
    __shared__ int starts_s[MAXN];

    for (int j = tid; j < 33 * 16 * 2; j += 256) rtab[j] = regtab[j];
    if (tid < MAXN) starts_s[tid] = starts[b * MAXN + tid];
    const float bs = bias_same[h];
    const float bd = bias_diff[h];
    __syncthreads();

    // ---- stage Q (rope + hi/lo) into persistent Qs ----
    const float* Qbh = q_in + (size_t)bh * Pp * Dd;
#pragma unroll
    for (int it = 0; it < 8; ++it) {
        int f  = tid + 256 * it;
        int p  = f >> 4;
        int dq = (f & 15) << 2;
        float4 x = ((const float4*)Qbh)[f];
        int fi = (dq & 31) >> 1;
        float4 cs;
        if (dq < 32) {
            int gpos = starts_s[p >> 2];
            cs = *(const float4*)(postab + (size_t)(gpos * 16 + fi) * 2);
        } else {
            int ridx = (p >> 2) + 1;
            cs = *(const float4*)(&rtab[(ridx * 16 + fi) * 2]);
        }
        float v0 = x.x * cs.x - x.y * cs.y;
        float v1 = x.x * cs.y + x.y * cs.x;
        float v2 = x.z * cs.z - x.w * cs.w;
        float v3 = x.z * cs.w + x.w * cs.z;
        bf16x4 hh, ll;
        hh[0] = (__bf16)v0; ll[0] = (__bf16)(v0 - (float)hh[0]);
        hh[1] = (__bf16)v1; ll[1] = (__bf16)(v1 - (float)hh[1]);
        hh[2] = (__bf16)v2; ll[2] = (__bf16)(v2 - (float)hh[2]);
        hh[3] = (__bf16)v3; ll[3] = (__bf16)(v3 - (float)hh[3]);
        *(bf16x4*)(Qs + SW(p, dq))      = hh;
        *(bf16x4*)(Qs + SW(p, 64 + dq)) = ll;
    }
    __syncthreads();

    // ---- Q fragments from LDS (r11-validated source) ----
    bf16x8 qh[2][2], ql[2][2];
#pragma unroll
    for (int c = 0; c < 2; ++c) {
        int pr = w * 32 + c * 16 + cl;
#pragma unroll
        for (int ks = 0; ks < 2; ++ks) {
            qh[ks][c] = *(const bf16x8*)(Qs + SW(pr, ks * 32 + g * 8));
            ql[ks][c] = *(const bf16x8*)(Qs + SW(pr, 64 + ks * 32 + g * 8));
        }
    }

    float m0 = -INFINITY, m1 = -INFINITY, l0 = 0.f, l1 = 0.f;
    f32x4 Oacc[2][4];
#pragma unroll
    for (int i0 = 0; i0 < 2; ++i0)
#pragma unroll
        for (int i1 = 0; i1 < 4; ++i1) Oacc[i0][i1] = (f32x4)0.f;

    const float* Kbh = k_in + (size_t)bh * Tt * Dd;
    const float* Vbh = v_in + (size_t)bh * Tt * Dd;

    for (int tt = 0; tt < NTILE; ++tt) {
        const int t0 = c0 + tt * 64;
        __syncthreads();   // B1: previous tile fully consumed
        if (tid < 64) regs_s[tid] = regions[b * Tt + t0 + tid];

        // ---- stage K tile: rope + hi/lo ----
#pragma unroll
        for (int it = 0; it < 4; ++it) {
            int f   = tid + 256 * it;
            int row = f >> 4;
            int dq  = (f & 15) << 2;
            float4 x = ((const float4*)(Kbh + (size_t)t0 * Dd))[f];
            int fi = (dq & 31) >> 1;
            float4 cs;
            if (dq < 32) {
                cs = *(const float4*)(postab + (size_t)((t0 + row) * 16 + fi) * 2);
            } else {
                int rg = regions[b * Tt + t0 + row];
                cs = *(const float4*)(&rtab[(rg * 16 + fi) * 2]);
            }
            float v0 = x.x * cs.x - x.y * cs.y;
            float v1 = x.x * cs.y + x.y * cs.x;
            float v2 = x.z * cs.z - x.w * cs.w;
            float v3 = x.z * cs.w + x.w * cs.z;
            bf16x4 hh, ll;
            hh[0] = (__bf16)v0; ll[0] = (__bf16)(v0 - (float)hh[0]);
            hh[1] = (__bf16)v1; ll[1] = (__bf16)(v1 - (float)hh[1]);
            hh[2] = (__bf16)v2; ll[2] = (__bf16)(v2 - (float)hh[2]);
            hh[3] = (__bf16)v3; ll[3] = (__bf16)(v3 - (float)hh[3]);
            *(bf16x4*)(Ks + SW(row, dq))      = hh;
            *(bf16x4*)(Ks + SW(row, 64 + dq)) = ll;
        }

        // ---- stage V tile transposed to [d][t], hi/lo ----
        {
            int dcol = tid & 63;
            int tg   = (tid >> 6) * 8;
#pragma unroll
            for (int jj = 0; jj < 2; ++jj) {
                int tl = jj * 32 + tg;
                bf16x8 hh, ll;
#pragma unroll
                for (int r = 0; r < 8; ++r) {
                    float vv = Vbh[(size_t)(t0 + tl + r) * Dd + dcol];
                    __bf16 hu = (__bf16)vv;
                    hh[r] = hu;
                    ll[r] = (__bf16)(vv - (float)hu);
                }
                *(bf16x8*)(Vs + SW(dcol, tl))      = hh;
                *(bf16x8*)(Vs + SW(dcol, 64 + tl)) = ll;
            }
        }
        __syncthreads();   // B2: staging complete

        // ---- QK^T MFMA, 6 k-steps: k_hi·q_hi + k_lo·q_hi + k_hi·q_lo ----
        f32x4 sacc[4][2];
#pragma unroll
        for (int mt = 0; mt < 4; ++mt) { sacc[mt][0] = (f32x4)0.f; sacc[mt][1] = (f32x4)0.f; }
        constexpr int AcolQ[6] = {0, 32, 64, 96, 0, 32};
#pragma unroll
        for (int s = 0; s < 6; ++s) {
            bf16x8 b0 = (s < 4) ? qh[s & 1][0] : ql[s & 1][0];
            bf16x8 b1 = (s < 4) ? qh[s & 1][1] : ql[s & 1][1];
#pragma unroll
            for (int mt = 0; mt < 4; ++mt) {
                int tr = mt * 16 + cl;
                bf16x8 ak = *(const bf16x8*)(Ks + SW(tr, AcolQ[s] + g * 8));
                sacc[mt][0] = __builtin_amdgcn_mfma_f32_16x16x32_bf16(ak, b0, sacc[mt][0], 0, 0, 0);
                sacc[mt][1] = __builtin_amdgcn_mfma_f32_16x16x32_bf16(ak, b1, sacc[mt][1], 0, 0, 0);
            }
        }

        // ---- scale + bias; per-column (p) tile max ----
        float tmax0 = -INFINITY, tmax1 = -INFINITY;
        const int ridx0 = ((w * 32 + cl) >> 2) + 1;
        const int ridx1 = ((w * 32 + 16 + cl) >> 2) + 1;
#pragma unroll
        for (int mt = 0; mt < 4; ++mt) {
#pragma unroll
            for (int r = 0; r < 4; ++r) {
                int rg = regs_s[mt * 16 + g * 4 + r];
                float s0 = sacc[mt][0][r] * 0.125f + ((ridx0 == rg) ? bs : bd);
                float s1 = sacc[mt][1][r] * 0.125f + ((ridx1 == rg) ? bs : bd);
                sacc[mt][0][r] = s0; sacc[mt][1][r] = s1;
                tmax0 = fmaxf(tmax0, s0); tmax1 = fmaxf(tmax1, s1);
            }
        }
        tmax0 = fmaxf(tmax0, __shfl_xor(tmax0, 16, 64));
        tmax0 = fmaxf(tmax0, __shfl_xor(tmax0, 32, 64));
        tmax1 = fmaxf(tmax1, __shfl_xor(tmax1, 16, 64));
        tmax1 = fmaxf(tmax1, __shfl_xor(tmax1, 32, 64));
        float mn0 = fmaxf(m0, tmax0), mn1 = fmaxf(m1, tmax1);
        float sc0 = __expf(m0 - mn0), sc1 = __expf(m1 - mn1);

        // ---- P = exp(s - m_new) -> bf16 hi/lo -> LDS; f32 row sums ----
        float rs0 = 0.f, rs1 = 0.f;
#pragma unroll
        for (int mt = 0; mt < 4; ++mt) {
            bf16x4 ph0, pl0, ph1, pl1;
#pragma unroll
            for (int r = 0; r < 4; ++r) {
                float e0 = __expf(sacc[mt][0][r] - mn0);
                float e1 = __expf(sacc[mt][1][r] - mn1);
                rs0 += e0; rs1 += e1;
                __bf16 u0 = (__bf16)e0, u1 = (__bf16)e1;
                ph0[r] = u0; pl0[r] = (__bf16)(e0 - (float)u0);
                ph1[r] = u1; pl1[r] = (__bf16)(e1 - (float)u1);
            }
            int trow = mt * 16 + g * 4;
            int pa = w * 32 + cl;
            *(bf16x4*)(Ps + SW(pa, trow))      = ph0;
            *(bf16x4*)(Ps + SW(pa, 64 + trow)) = pl0;
            pa += 16;
            *(bf16x4*)(Ps + SW(pa, trow))      = ph1;
            *(bf16x4*)(Ps + SW(pa, 64 + trow)) = pl1;
        }
        rs0 += __shfl_xor(rs0, 16, 64); rs0 += __shfl_xor(rs0, 32, 64);
        rs1 += __shfl_xor(rs1, 16, 64); rs1 += __shfl_xor(rs1, 32, 64);
        l0 = l0 * sc0 + rs0; m0 = mn0;
        l1 = l1 * sc1 + rs1; m1 = mn1;

        __syncthreads();   // B3: P visible

        // ---- rescale O ----
#pragma unroll
        for (int r = 0; r < 4; ++r) {
            float f0 = __shfl(sc0, g * 4 + r, 64);
            float f1 = __shfl(sc1, g * 4 + r, 64);
#pragma unroll
            for (int nt = 0; nt < 4; ++nt) {
                Oacc[0][nt][r] *= f0;
                Oacc[1][nt][r] *= f1;
            }
        }

        // ---- PV: O += P_hi·V_hi + P_hi·V_lo + P_lo·V_hi ----
        constexpr int AcolP[6] = {0, 32, 0, 32, 64, 96};
        constexpr int BcolV[6] = {0, 32, 64, 96, 0, 32};
#pragma unroll
        for (int s = 0; s < 6; ++s) {
            bf16x8 ap0, ap1;
            {
                int pp = w * 32 + cl;
                ap0 = *(const bf16x8*)(Ps + SW(pp, AcolP[s] + g * 8));
                ap1 = *(const bf16x8*)(Ps + SW(pp + 16, AcolP[s] + g * 8));
            }
#pragma unroll
            for (int nt = 0; nt < 4; ++nt) {
                int d = nt * 16 + cl;
                bf16x8 bv = *(const bf16x8*)(Vs + SW(d, BcolV[s] + g * 8));
                Oacc[0][nt] = __builtin_amdgcn_mfma_f32_16x16x32_bf16(ap0, bv, Oacc[0][nt], 0, 0, 0);
                Oacc[1][nt] = __builtin_amdgcn_mfma_f32_16x16x32_bf16(ap1, bv, Oacc[1][nt], 0, 0, 0);
            }
        }
    }

    // ---- write partials ----
    size_t obase = (size_t)(bh * NS + chunk) * Pp * Dd;
#pragma unroll
    for (int mtp = 0; mtp < 2; ++mtp)
#pragma unroll
        for (int nt = 0; nt < 4; ++nt)
#pragma unroll
            for (int r = 0; r < 4; ++r) {
                int pb = w * 32 + mtp * 16 + g * 4 + r;
                int d  = nt * 16 + cl;
                pO[obase + pb * 64 + d] = Oacc[mtp][nt][r];
            }
    if (g == 0) {
        size_t mlb = (size_t)(bh * NS + chunk) * Pp;
        int p0 = w * 32 + cl;
        *(float2*)(pML + (mlb + p0) * 2)      = make_float2(m0, l0);
        *(float2*)(pML + (mlb + p0 + 16) * 2) = make_float2(m1, l1);
    }
}

// ---------------- combine partials across T-chunks ----------------
__global__ void k_combine(const float* __restrict__ pO, const float* __restrict__ pML,
                          float* __restrict__ out, int NS) {
    int bh = blockIdx.x >> 2;
    int pq = blockIdx.x & 3;
    int d  = threadIdx.x & 63;
    int ps = threadIdx.x >> 6;
    for (int pp = 0; pp < 8; ++pp) {
        int p = pq * 32 + pp * 4 + ps;
        float M = -INFINITY;
        float mv[8], lv[8];
        for (int c = 0; c < NS; ++c) {
            float2 ml = *(const float2*)(pML + ((size_t)(bh * NS + c) * Pp + p) * 2);
            mv[c] = ml.x; lv[c] = ml.y;
            M = fmaxf(M, ml.x);
        }
        float L = 0.f, o = 0.f;
        for (int c = 0; c < NS; ++c) {
            float wgt = __expf(mv[c] - M);
            L += wgt * lv[c];
            o += wgt * pO[((size_t)(bh * NS + c) * Pp + p) * Dd + d];
        }
        out[((size_t)bh * Pp + p) * Dd + d] = o / L;
    }
}

// ---------------- launcher ----------------
extern "C" void kernel_launch(void* const* d_in, const int* in_sizes, int n_in,
                              void* d_out, int out_size, void* d_ws, size_t ws_size,
                              hipStream_t stream) {
    const float* q         = (const float*)d_in[0];
    const float* k         = (const float*)d_in[1];
    const float* v         = (const float*)d_in[2];
    const int*   regions   = (const int*)d_in[3];
    const float* bias_same = (const float*)d_in[7];
    const float* bias_diff = (const float*)d_in[8];

    float* ws     = (float*)d_ws;
    float* postab = ws;
    float* regtab = postab + Tt * 16 * 2;
    int*   starts = (int*)(regtab + 33 * 16 * 2);
    float* pbase  = (float*)(starts + 128);
    size_t fixed_b = (size_t)((char*)pbase - (char*)ws);

    int NS = 8;
    while (NS > 1 && fixed_b + (size_t)BHc * NS * Pp * (Dd + 2) * 4 > ws_size) NS >>= 1;
    float* pO  = pbase;
    float* pML = pO + (size_t)BHc * NS * Pp * Dd;

    k_postab<<<dim3(Tt * 16 / 256), dim3(256), 0, stream>>>(postab);
    k_prep<<<dim3(1), dim3(704), 0, stream>>>(regions, regtab, starts);
    k_attn<<<dim3(BHc * NS), dim3(256), 0, stream>>>(q, k, v, regions, bias_same, bias_diff,
                                                     postab, regtab, starts, pO, pML, NS);
    k_combine<<<dim3(BHc * 4), dim3(256), 0, stream>>>(pO, pML, (float*)d_out, NS);
}

// Round 13
// 91.744 us; speedup vs baseline: 61.6722x; 1.5087x over previous
//
#include <hip/hip_runtime.h>
#include <hip/hip_bf16.h>
#include <math.h>

#define Bb   4
#define Hh   16
#define Tt   4096
#define Dd   64
#define Pp   128
#define MAXN 32
#define BHc  64   // B*H

typedef __bf16 bf16x8 __attribute__((ext_vector_type(8)));
typedef __bf16 bf16x4 __attribute__((ext_vector_type(4)));
typedef float  f32x4  __attribute__((ext_vector_type(4)));

// swizzled element index into a [row][128] __bf16 LDS tile
#define SW(row, col) (((row) * 128) + ((col) ^ (((row) & 15) << 3)))

// ---------------- precompute: cos/sin table for global positions ----------------
__global__ void k_postab(float* __restrict__ postab) {
    int idx = blockIdx.x * blockDim.x + threadIdx.x;
    if (idx >= Tt * 16) return;
    int pos = idx >> 4, fi = idx & 15;
    float inv = (float)pow(10000.0, -(double)fi / 16.0);
    float ang = (float)pos * inv;
    postab[idx * 2 + 0] = cosf(ang);
    postab[idx * 2 + 1] = sinf(ang);
}

// ---------------- precompute: region starts + region cos/sin table ----------------
__global__ void k_prep(const int* __restrict__ regions, float* __restrict__ regtab,
                       int* __restrict__ starts) {
    int i = threadIdx.x;
    if (i < Bb * MAXN) {
        int b = i >> 5, n = (i & 31) + 1;
        const int* r = regions + b * Tt;
        int lo = 0, hi = Tt;
        while (lo < hi) { int mid = (lo + hi) >> 1; if (r[mid] < n) lo = mid + 1; else hi = mid; }
        starts[i] = (lo < Tt && r[lo] == n) ? lo : 0;
    }
    int j = i - Bb * MAXN;
    if (j >= 0 && j < 33 * 16) {
        int pos = j >> 4, fi = j & 15;
        float inv = (float)pow(10000.0, -(double)fi / 16.0);
        float ang = (float)pos * inv;
        regtab[j * 2 + 0] = cosf(ang);
        regtab[j * 2 + 1] = sinf(ang);
    }
}

// ---------------- main flash-attention kernel: 8 waves (2/SIMD), r12 math ----------------
// Each wave owns 16 p-columns (p = w*16 + cl). Q persistent in LDS (validated).
__global__ __launch_bounds__(512) void k_attn(
    const float* __restrict__ q_in, const float* __restrict__ k_in,
    const float* __restrict__ v_in, const int* __restrict__ regions,
    const float* __restrict__ bias_same, const float* __restrict__ bias_diff,
    const float* __restrict__ postab, const float* __restrict__ regtab,
    const int* __restrict__ starts, float* __restrict__ pO,
    float* __restrict__ pML, int NS)
{
    const int bid   = blockIdx.x;
    const int chunk = bid % NS;
    const int bh    = bid / NS;
    const int b     = bh >> 4;
    const int h     = bh & 15;
    const int C     = Tt / NS;
    const int NTILE = C >> 6;
    const int c0    = chunk * C;

    const int tid = threadIdx.x;
    const int w  = tid >> 6;        // wave 0..7, owns p cols [16w, 16w+16)
    const int l  = tid & 63;
    const int cl = l & 15;
    const int g  = l >> 4;

    __shared__ __align__(16) __bf16 Qs[Pp * 128];    // q hi/lo, PERSISTENT
    __shared__ __align__(16) __bf16 Ks[64 * 128];
    __shared__ __align__(16) __bf16 Vs[64 * 128];
    __shared__ __align__(16) __bf16 Ps[Pp * 128];
    __shared__ __align__(16) float rtab[33 * 16 * 2];
    __shared__ int regs_s[64];
    __shared__ int starts_s[MAXN];

    for (int j = tid; j < 33 * 16 * 2; j += 512) rtab[j] = regtab[j];
    if (tid < MAXN) starts_s[tid] = starts[b * MAXN + tid];
    const float bs = bias_same[h];
    const float bd = bias_diff[h];
    __syncthreads();

    // ---- stage Q (rope + hi/lo) into persistent Qs ----
    const float* Qbh = q_in + (size_t)bh * Pp * Dd;
#pragma unroll
    for (int it = 0; it < 4; ++it) {
        int f  = tid + 512 * it;
        int p  = f >> 4;
        int dq = (f & 15) << 2;
        float4 x = ((const float4*)Qbh)[f];
        int fi = (dq & 31) >> 1;
        float4 cs;
        if (dq < 32) {
            int gpos = starts_s[p >> 2];
            cs = *(const float4*)(postab + (size_t)(gpos * 16 + fi) * 2);
        } else {
            int ridx = (p >> 2) + 1;
            cs = *(const float4*)(&rtab[(ridx * 16 + fi) * 2]);
        }
        float v0 = x.x * cs.x - x.y * cs.y;
        float v1 = x.x * cs.y + x.y * cs.x;
        float v2 = x.z * cs.z - x.w * cs.w;
        float v3 = x.z * cs.w + x.w * cs.z;
        bf16x4 hh, ll;
        hh[0] = (__bf16)v0; ll[0] = (__bf16)(v0 - (float)hh[0]);
        hh[1] = (__bf16)v1; ll[1] = (__bf16)(v1 - (float)hh[1]);
        hh[2] = (__bf16)v2; ll[2] = (__bf16)(v2 - (float)hh[2]);
        hh[3] = (__bf16)v3; ll[3] = (__bf16)(v3 - (float)hh[3]);
        *(bf16x4*)(Qs + SW(p, dq))      = hh;
        *(bf16x4*)(Qs + SW(p, 64 + dq)) = ll;
    }
    __syncthreads();

    // ---- Q fragments from LDS (validated source), 16 cols per wave ----
    bf16x8 qh[2], ql[2];
    {
        int pr = w * 16 + cl;
#pragma unroll
        for (int ks = 0; ks < 2; ++ks) {
            qh[ks] = *(const bf16x8*)(Qs + SW(pr, ks * 32 + g * 8));
            ql[ks] = *(const bf16x8*)(Qs + SW(pr, 64 + ks * 32 + g * 8));
        }
    }

    float m0 = -INFINITY, l0 = 0.f;
    f32x4 Oacc[4];
#pragma unroll
    for (int i1 = 0; i1 < 4; ++i1) Oacc[i1] = (f32x4)0.f;

    const float* Kbh = k_in + (size_t)bh * Tt * Dd;
    const float* Vbh = v_in + (size_t)bh * Tt * Dd;

    for (int tt = 0; tt < NTILE; ++tt) {
        const int t0 = c0 + tt * 64;
        __syncthreads();   // B1: previous tile fully consumed
        if (tid < 64) regs_s[tid] = regions[b * Tt + t0 + tid];

        // ---- stage K tile: rope + hi/lo ----
#pragma unroll
        for (int it = 0; it < 2; ++it) {
            int f   = tid + 512 * it;
            int row = f >> 4;
            int dq  = (f & 15) << 2;
            float4 x = ((const float4*)(Kbh + (size_t)t0 * Dd))[f];
            int fi = (dq & 31) >> 1;
            float4 cs;
            if (dq < 32) {
                cs = *(const float4*)(postab + (size_t)((t0 + row) * 16 + fi) * 2);
            } else {
                int rg = regions[b * Tt + t0 + row];
                cs = *(const float4*)(&rtab[(rg * 16 + fi) * 2]);
            }
            float v0 = x.x * cs.x - x.y * cs.y;
            float v1 = x.x * cs.y + x.y * cs.x;
            float v2 = x.z * cs.z - x.w * cs.w;
            float v3 = x.z * cs.w + x.w * cs.z;
            bf16x4 hh, ll;
            hh[0] = (__bf16)v0; ll[0] = (__bf16)(v0 - (float)hh[0]);
            hh[1] = (__bf16)v1; ll[1] = (__bf16)(v1 - (float)hh[1]);
            hh[2] = (__bf16)v2; ll[2] = (__bf16)(v2 - (float)hh[2]);
            hh[3] = (__bf16)v3; ll[3] = (__bf16)(v3 - (float)hh[3]);
            *(bf16x4*)(Ks + SW(row, dq))      = hh;
            *(bf16x4*)(Ks + SW(row, 64 + dq)) = ll;
        }

        // ---- stage V tile transposed to [d][t], hi/lo (one pass, 512 threads) ----
        {
            int dcol = tid & 63;
            int tl   = (tid >> 6) * 8;
            bf16x8 hh, ll;
#pragma unroll
            for (int r = 0; r < 8; ++r) {
                float vv = Vbh[(size_t)(t0 + tl + r) * Dd + dcol];
                __bf16 hu = (__bf16)vv;
                hh[r] = hu;
                ll[r] = (__bf16)(vv - (float)hu);
            }
            *(bf16x8*)(Vs + SW(dcol, tl))      = hh;
            *(bf16x8*)(Vs + SW(dcol, 64 + tl)) = ll;
        }
        __syncthreads();   // B2: staging complete

        // ---- QK^T MFMA, 6 k-steps: k_hi·q_hi + k_lo·q_hi + k_hi·q_lo ----
        f32x4 sacc[4];
#pragma unroll
        for (int mt = 0; mt < 4; ++mt) sacc[mt] = (f32x4)0.f;
        constexpr int AcolQ[6] = {0, 32, 64, 96, 0, 32};
#pragma unroll
        for (int s = 0; s < 6; ++s) {
            bf16x8 b0 = (s < 4) ? qh[s & 1] : ql[s & 1];
#pragma unroll
            for (int mt = 0; mt < 4; ++mt) {
                int tr = mt * 16 + cl;
                bf16x8 ak = *(const bf16x8*)(Ks + SW(tr, AcolQ[s] + g * 8));
                sacc[mt] = __builtin_amdgcn_mfma_f32_16x16x32_bf16(ak, b0, sacc[mt], 0, 0, 0);
            }
        }

        // ---- scale + bias; per-column (p) tile max ----
        float tmax0 = -INFINITY;
        const int ridx0 = ((w * 16 + cl) >> 2) + 1;
#pragma unroll
        for (int mt = 0; mt < 4; ++mt) {
#pragma unroll
            for (int r = 0; r < 4; ++r) {
                int rg = regs_s[mt * 16 + g * 4 + r];
                float s0 = sacc[mt][r] * 0.125f + ((ridx0 == rg) ? bs : bd);
                sacc[mt][r] = s0;
                tmax0 = fmaxf(tmax0, s0);
            }
        }
        tmax0 = fmaxf(tmax0, __shfl_xor(tmax0, 16, 64));
        tmax0 = fmaxf(tmax0, __shfl_xor(tmax0, 32, 64));
        float mn0 = fmaxf(m0, tmax0);
        float sc0 = __expf(m0 - mn0);

        // ---- P = exp(s - m_new) -> bf16 hi/lo -> LDS; f32 row sums ----
        float rs0 = 0.f;
#pragma unroll
        for (int mt = 0; mt < 4; ++mt) {
            bf16x4 ph0, pl0;
#pragma unroll
            for (int r = 0; r < 4; ++r) {
                float e0 = __expf(sacc[mt][r] - mn0);
                rs0 += e0;
                __bf16 u0 = (__bf16)e0;
                ph0[r] = u0; pl0[r] = (__bf16)(e0 - (float)u0);
            }
            int trow = mt * 16 + g * 4;
            int pa = w * 16 + cl;
            *(bf16x4*)(Ps + SW(pa, trow))      = ph0;
            *(bf16x4*)(Ps + SW(pa, 64 + trow)) = pl0;
        }
        rs0 += __shfl_xor(rs0, 16, 64); rs0 += __shfl_xor(rs0, 32, 64);
        l0 = l0 * sc0 + rs0; m0 = mn0;

        __syncthreads();   // B3: P visible

        // ---- rescale O (factor per output row p = w*16 + g*4 + r) ----
#pragma unroll
        for (int r = 0; r < 4; ++r) {
            float f0 = __shfl(sc0, g * 4 + r, 64);
#pragma unroll
            for (int nt = 0; nt < 4; ++nt) Oacc[nt][r] *= f0;
        }

        // ---- PV: O += P_hi·V_hi + P_hi·V_lo + P_lo·V_hi ----
        constexpr int AcolP[6] = {0, 32, 0, 32, 64, 96};
        constexpr int BcolV[6] = {0, 32, 64, 96, 0, 32};
#pragma unroll
        for (int s = 0; s < 6; ++s) {
            bf16x8 ap0;
            {
                int pp = w * 16 + cl;
                ap0 = *(const bf16x8*)(Ps + SW(pp, AcolP[s] + g * 8));
            }
#pragma unroll
            for (int nt = 0; nt < 4; ++nt) {
                int d = nt * 16 + cl;
                bf16x8 bv = *(const bf16x8*)(Vs + SW(d, BcolV[s] + g * 8));
                Oacc[nt] = __builtin_amdgcn_mfma_f32_16x16x32_bf16(ap0, bv, Oacc[nt], 0, 0, 0);
            }
        }
    }

    // ---- write partials ----
    size_t obase = (size_t)(bh * NS + chunk) * Pp * Dd;
#pragma unroll
    for (int nt = 0; nt < 4; ++nt)
#pragma unroll
        for (int r = 0; r < 4; ++r) {
            int pb = w * 16 + g * 4 + r;
            int d  = nt * 16 + cl;
            pO[obase + pb * 64 + d] = Oacc[nt][r];
        }
    if (g == 0) {
        size_t mlb = (size_t)(bh * NS + chunk) * Pp;
        int p0 = w * 16 + cl;
        *(float2*)(pML + (mlb + p0) * 2) = make_float2(m0, l0);
    }
}

// ---------------- combine partials across T-chunks ----------------
__global__ void k_combine(const float* __restrict__ pO, const float* __restrict__ pML,
                          float* __restrict__ out, int NS) {
    int bh = blockIdx.x >> 2;
    int pq = blockIdx.x & 3;
    int d  = threadIdx.x & 63;
    int ps = threadIdx.x >> 6;
    for (int pp = 0; pp < 8; ++pp) {
        int p = pq * 32 + pp * 4 + ps;
        float M = -INFINITY;
        float mv[8], lv[8];
        for (int c = 0; c < NS; ++c) {
            float2 ml = *(const float2*)(pML + ((size_t)(bh * NS + c) * Pp + p) * 2);
            mv[c] = ml.x; lv[c] = ml.y;
            M = fmaxf(M, ml.x);
        }
        float L = 0.f, o = 0.f;
        for (int c = 0; c < NS; ++c) {
            float wgt = __expf(mv[c] - M);
            L += wgt * lv[c];
            o += wgt * pO[((size_t)(bh * NS + c) * Pp + p) * Dd + d];
        }
        out[((size_t)bh * Pp + p) * Dd + d] = o / L;
    }
}

// ---------------- launcher ----------------
extern "C" void kernel_launch(void* const* d_in, const int* in_sizes, int n_in,
                              void* d_out, int out_size, void* d_ws, size_t ws_size,
                              hipStream_t stream) {
    const float* q         = (const float*)d_in[0];
    const float* k         = (const float*)d_in[1];
    const float* v         = (const float*)d_in[2];
    const int*   regions   = (const int*)d_in[3];
    const float* bias_same = (const float*)d_in[7];
    const float* bias_diff = (const float*)d_in[8];

    float* ws     = (float*)d_ws;
    float* postab = ws;
    float* regtab = postab + Tt * 16 * 2;
    int*   starts = (int*)(regtab + 33 * 16 * 2);
    float* pbase  = (float*)(starts + 128);
    size_t fixed_b = (size_t)((char*)pbase - (char*)ws);

    int NS = 4;   // 256 blocks = exactly 1 per CU, single round
    while (NS > 1 && fixed_b + (size_t)BHc * NS * Pp * (Dd + 2) * 4 > ws_size) NS >>= 1;
    float* pO  = pbase;
    float* pML = pO + (size_t)BHc * NS * Pp * Dd;

    k_postab<<<dim3(Tt * 16 / 256), dim3(256), 0, stream>>>(postab);
    k_prep<<<dim3(1), dim3(704), 0, stream>>>(regions, regtab, starts);
    k_attn<<<dim3(BHc * NS), dim3(512), 0, stream>>>(q, k, v, regions, bias_same, bias_diff,
                                                     postab, regtab, starts, pO, pML, NS);
    k_combine<<<dim3(BHc * 4), dim3(256), 0, stream>>>(pO, pML, (float*)d_out, NS);
}

// Round 14
// 85.218 us; speedup vs baseline: 66.3949x; 1.0766x over previous
//
#include <hip/hip_runtime.h>
#include <hip/hip_bf16.h>
#include <math.h>

#define Bb   4
#define Hh   16
#define Tt   4096
#define Dd   64
#define Pp   128
#define MAXN 32
#define BHc  64   // B*H

typedef __bf16 bf16x8 __attribute__((ext_vector_type(8)));
typedef __bf16 bf16x4 __attribute__((ext_vector_type(4)));
typedef float  f32x4  __attribute__((ext_vector_type(4)));

// swizzled element index into a [row][128] __bf16 LDS tile
#define SW(row, col) (((row) * 128) + ((col) ^ (((row) & 15) << 3)))

// ---------------- precompute: cos/sin table for global positions ----------------
__global__ void k_postab(float* __restrict__ postab) {
    int idx = blockIdx.x * blockDim.x + threadIdx.x;
    if (idx >= Tt * 16) return;
    int pos = idx >> 4, fi = idx & 15;
    float inv = (float)pow(10000.0, -(double)fi / 16.0);
    float ang = (float)pos * inv;
    postab[idx * 2 + 0] = cosf(ang);
    postab[idx * 2 + 1] = sinf(ang);
}

// ---------------- precompute: region starts + region cos/sin table ----------------
__global__ void k_prep(const int* __restrict__ regions, float* __restrict__ regtab,
                       int* __restrict__ starts) {
    int i = threadIdx.x;
    if (i < Bb * MAXN) {
        int b = i >> 5, n = (i & 31) + 1;
        const int* r = regions + b * Tt;
        int lo = 0, hi = Tt;
        while (lo < hi) { int mid = (lo + hi) >> 1; if (r[mid] < n) lo = mid + 1; else hi = mid; }
        starts[i] = (lo < Tt && r[lo] == n) ? lo : 0;
    }
    int j = i - Bb * MAXN;
    if (j >= 0 && j < 33 * 16) {
        int pos = j >> 4, fi = j & 15;
        float inv = (float)pow(10000.0, -(double)fi / 16.0);
        float ang = (float)pos * inv;
        regtab[j * 2 + 0] = cosf(ang);
        regtab[j * 2 + 1] = sinf(ang);
    }
}

// ---------------- main flash-attention kernel: 8 waves + register prefetch (T14) ----------------
__global__ __launch_bounds__(512) void k_attn(
    const float* __restrict__ q_in, const float* __restrict__ k_in,
    const float* __restrict__ v_in, const int* __restrict__ regions,
    const float* __restrict__ bias_same, const float* __restrict__ bias_diff,
    const float* __restrict__ postab, const float* __restrict__ regtab,
    const int* __restrict__ starts, float* __restrict__ pO,
    float* __restrict__ pML, int NS)
{
    const int bid   = blockIdx.x;
    const int chunk = bid % NS;
    const int bh    = bid / NS;
    const int b     = bh >> 4;
    const int h     = bh & 15;
    const int C     = Tt / NS;
    const int NTILE = C >> 6;
    const int c0    = chunk * C;

    const int tid = threadIdx.x;
    const int w  = tid >> 6;        // wave 0..7, owns p cols [16w, 16w+16)
    const int l  = tid & 63;
    const int cl = l & 15;
    const int g  = l >> 4;

    __shared__ __align__(16) __bf16 Qs[Pp * 128];    // q hi/lo, PERSISTENT
    __shared__ __align__(16) __bf16 Ks[64 * 128];
    __shared__ __align__(16) __bf16 Vs[64 * 128];
    __shared__ __align__(16) __bf16 Ps[Pp * 128];
    __shared__ __align__(16) float rtab[33 * 16 * 2];
    __shared__ int regs_s[64];
    __shared__ int starts_s[MAXN];

    for (int j = tid; j < 33 * 16 * 2; j += 512) rtab[j] = regtab[j];
    if (tid < MAXN) starts_s[tid] = starts[b * MAXN + tid];
    const float bs = bias_same[h];
    const float bd = bias_diff[h];
    __syncthreads();

    // ---- stage Q (rope + hi/lo) into persistent Qs ----
    const float* Qbh = q_in + (size_t)bh * Pp * Dd;
#pragma unroll
    for (int it = 0; it < 4; ++it) {
        int f  = tid + 512 * it;
        int p  = f >> 4;
        int dq = (f & 15) << 2;
        float4 x = ((const float4*)Qbh)[f];
        int fi = (dq & 31) >> 1;
        float4 cs;
        if (dq < 32) {
            int gpos = starts_s[p >> 2];
            cs = *(const float4*)(postab + (size_t)(gpos * 16 + fi) * 2);
        } else {
            int ridx = (p >> 2) + 1;
            cs = *(const float4*)(&rtab[(ridx * 16 + fi) * 2]);
        }
        float v0 = x.x * cs.x - x.y * cs.y;
        float v1 = x.x * cs.y + x.y * cs.x;
        float v2 = x.z * cs.z - x.w * cs.w;
        float v3 = x.z * cs.w + x.w * cs.z;
        bf16x4 hh, ll;
        hh[0] = (__bf16)v0; ll[0] = (__bf16)(v0 - (float)hh[0]);
        hh[1] = (__bf16)v1; ll[1] = (__bf16)(v1 - (float)hh[1]);
        hh[2] = (__bf16)v2; ll[2] = (__bf16)(v2 - (float)hh[2]);
        hh[3] = (__bf16)v3; ll[3] = (__bf16)(v3 - (float)hh[3]);
        *(bf16x4*)(Qs + SW(p, dq))      = hh;
        *(bf16x4*)(Qs + SW(p, 64 + dq)) = ll;
    }
    __syncthreads();

    // ---- Q fragments from LDS (validated source), 16 cols per wave ----
    bf16x8 qh[2], ql[2];
    {
        int pr = w * 16 + cl;
#pragma unroll
        for (int ks = 0; ks < 2; ++ks) {
            qh[ks] = *(const bf16x8*)(Qs + SW(pr, ks * 32 + g * 8));
            ql[ks] = *(const bf16x8*)(Qs + SW(pr, 64 + ks * 32 + g * 8));
        }
    }

    float m0 = -INFINITY, l0 = 0.f;
    f32x4 Oacc[4];
#pragma unroll
    for (int i1 = 0; i1 < 4; ++i1) Oacc[i1] = (f32x4)0.f;

    const float* Kbh = k_in + (size_t)bh * Tt * Dd;
    const float* Vbh = v_in + (size_t)bh * Tt * Dd;

    // ---- T14 prefetch state: next tile's raw data in registers ----
    float4 kx[2], kcs[2];
    int    krg[2], rreg;
    float  vx[8];
    auto prefetch = [&](int t0n) {
#pragma unroll
        for (int it = 0; it < 2; ++it) {
            int f   = tid + 512 * it;
            int row = f >> 4;
            int dq  = (f & 15) << 2;
            int fi  = (dq & 31) >> 1;
            kx[it]  = ((const float4*)(Kbh + (size_t)t0n * Dd))[f];
            kcs[it] = *(const float4*)(postab + (size_t)((t0n + row) * 16 + fi) * 2);
            krg[it] = regions[b * Tt + t0n + row];
        }
        {
            int dcol = tid & 63;
            int tl   = (tid >> 6) * 8;
#pragma unroll
            for (int r = 0; r < 8; ++r)
                vx[r] = Vbh[(size_t)(t0n + tl + r) * Dd + dcol];
        }
        rreg = (tid < 64) ? regions[b * Tt + t0n + tid] : 0;
    };
    prefetch(c0);

    for (int tt = 0; tt < NTILE; ++tt) {
        const int t0 = c0 + tt * 64;
        __syncthreads();   // B1: previous tile fully consumed
        if (tid < 64) regs_s[tid] = rreg;

        // ---- convert prefetched K tile: rope + hi/lo -> LDS ----
#pragma unroll
        for (int it = 0; it < 2; ++it) {
            int f   = tid + 512 * it;
            int row = f >> 4;
            int dq  = (f & 15) << 2;
            float4 x = kx[it];
            float4 cs;
            if (dq < 32) {
                cs = kcs[it];
            } else {
                int rg = krg[it];
                cs = *(const float4*)(&rtab[(rg * 16 + ((dq & 31) >> 1)) * 2]);
            }
            float v0 = x.x * cs.x - x.y * cs.y;
            float v1 = x.x * cs.y + x.y * cs.x;
            float v2 = x.z * cs.z - x.w * cs.w;
            float v3 = x.z * cs.w + x.w * cs.z;
            bf16x4 hh, ll;
            hh[0] = (__bf16)v0; ll[0] = (__bf16)(v0 - (float)hh[0]);
            hh[1] = (__bf16)v1; ll[1] = (__bf16)(v1 - (float)hh[1]);
            hh[2] = (__bf16)v2; ll[2] = (__bf16)(v2 - (float)hh[2]);
            hh[3] = (__bf16)v3; ll[3] = (__bf16)(v3 - (float)hh[3]);
            *(bf16x4*)(Ks + SW(row, dq))      = hh;
            *(bf16x4*)(Ks + SW(row, 64 + dq)) = ll;
        }

        // ---- convert prefetched V tile (transposed [d][t]) -> LDS ----
        {
            int dcol = tid & 63;
            int tl   = (tid >> 6) * 8;
            bf16x8 hh, ll;
#pragma unroll
            for (int r = 0; r < 8; ++r) {
                float vv = vx[r];
                __bf16 hu = (__bf16)vv;
                hh[r] = hu;
                ll[r] = (__bf16)(vv - (float)hu);
            }
            *(bf16x8*)(Vs + SW(dcol, tl))      = hh;
            *(bf16x8*)(Vs + SW(dcol, 64 + tl)) = ll;
        }
        __syncthreads();   // B2: staging complete

        // ---- issue next tile's loads (latency hides under this tile's compute) ----
        if (tt + 1 < NTILE) prefetch(t0 + 64);

        // ---- QK^T MFMA, 6 k-steps: k_hi·q_hi + k_lo·q_hi + k_hi·q_lo ----
        f32x4 sacc[4];
#pragma unroll
        for (int mt = 0; mt < 4; ++mt) sacc[mt] = (f32x4)0.f;
        constexpr int AcolQ[6] = {0, 32, 64, 96, 0, 32};
#pragma unroll
        for (int s = 0; s < 6; ++s) {
            bf16x8 b0 = (s < 4) ? qh[s & 1] : ql[s & 1];
#pragma unroll
            for (int mt = 0; mt < 4; ++mt) {
                int tr = mt * 16 + cl;
                bf16x8 ak = *(const bf16x8*)(Ks + SW(tr, AcolQ[s] + g * 8));
                sacc[mt] = __builtin_amdgcn_mfma_f32_16x16x32_bf16(ak, b0, sacc[mt], 0, 0, 0);
            }
        }

        // ---- scale + bias; per-column (p) tile max ----
        float tmax0 = -INFINITY;
        const int ridx0 = ((w * 16 + cl) >> 2) + 1;
#pragma unroll
        for (int mt = 0; mt < 4; ++mt) {
#pragma unroll
            for (int r = 0; r < 4; ++r) {
                int rg = regs_s[mt * 16 + g * 4 + r];
                float s0 = sacc[mt][r] * 0.125f + ((ridx0 == rg) ? bs : bd);
                sacc[mt][r] = s0;
                tmax0 = fmaxf(tmax0, s0);
            }
        }
        tmax0 = fmaxf(tmax0, __shfl_xor(tmax0, 16, 64));
        tmax0 = fmaxf(tmax0, __shfl_xor(tmax0, 32, 64));
        float mn0 = fmaxf(m0, tmax0);
        float sc0 = __expf(m0 - mn0);

        // ---- P = exp(s - m_new) -> bf16 hi/lo -> LDS; f32 row sums ----
        float rs0 = 0.f;
#pragma unroll
        for (int mt = 0; mt < 4; ++mt) {
            bf16x4 ph0, pl0;
#pragma unroll
            for (int r = 0; r < 4; ++r) {
                float e0 = __expf(sacc[mt][r] - mn0);
                rs0 += e0;
                __bf16 u0 = (__bf16)e0;
                ph0[r] = u0; pl0[r] = (__bf16)(e0 - (float)u0);
            }
            int trow = mt * 16 + g * 4;
            int pa = w * 16 + cl;
            *(bf16x4*)(Ps + SW(pa, trow))      = ph0;
            *(bf16x4*)(Ps + SW(pa, 64 + trow)) = pl0;
        }
        rs0 += __shfl_xor(rs0, 16, 64); rs0 += __shfl_xor(rs0, 32, 64);
        l0 = l0 * sc0 + rs0; m0 = mn0;

        __syncthreads();   // B3: P visible

        // ---- rescale O (factor per output row p = w*16 + g*4 + r) ----
#pragma unroll
        for (int r = 0; r < 4; ++r) {
            float f0 = __shfl(sc0, g * 4 + r, 64);
#pragma unroll
            for (int nt = 0; nt < 4; ++nt) Oacc[nt][r] *= f0;
        }

        // ---- PV: O += P_hi·V_hi + P_hi·V_lo + P_lo·V_hi ----
        constexpr int AcolP[6] = {0, 32, 0, 32, 64, 96};
        constexpr int BcolV[6] = {0, 32, 64, 96, 0, 32};
#pragma unroll
        for (int s = 0; s < 6; ++s) {
            bf16x8 ap0;
            {
                int pp = w * 16 + cl;
                ap0 = *(const bf16x8*)(Ps + SW(pp, AcolP[s] + g * 8));
            }
#pragma unroll
            for (int nt = 0; nt < 4; ++nt) {
                int d = nt * 16 + cl;
                bf16x8 bv = *(const bf16x8*)(Vs + SW(d, BcolV[s] + g * 8));
                Oacc[nt] = __builtin_amdgcn_mfma_f32_16x16x32_bf16(ap0, bv, Oacc[nt], 0, 0, 0);
            }
        }
    }

    // ---- write partials ----
    size_t obase = (size_t)(bh * NS + chunk) * Pp * Dd;
#pragma unroll
    for (int nt = 0; nt < 4; ++nt)
#pragma unroll
        for (int r = 0; r < 4; ++r) {
            int pb = w * 16 + g * 4 + r;
            int d  = nt * 16 + cl;
            pO[obase + pb * 64 + d] = Oacc[nt][r];
        }
    if (g == 0) {
        size_t mlb = (size_t)(bh * NS + chunk) * Pp;
        int p0 = w * 16 + cl;
        *(float2*)(pML + (mlb + p0) * 2) = make_float2(m0, l0);
    }
}

// ---------------- combine partials across T-chunks ----------------
__global__ void k_combine(const float* __restrict__ pO, const float* __restrict__ pML,
                          float* __restrict__ out, int NS) {
    int bh = blockIdx.x >> 2;
    int pq = blockIdx.x & 3;
    int d  = threadIdx.x & 63;
    int ps = threadIdx.x >> 6;
    for (int pp = 0; pp < 8; ++pp) {
        int p = pq * 32 + pp * 4 + ps;
        float M = -INFINITY;
        float mv[8], lv[8];
        for (int c = 0; c < NS; ++c) {
            float2 ml = *(const float2*)(pML + ((size_t)(bh * NS + c) * Pp + p) * 2);
            mv[c] = ml.x; lv[c] = ml.y;
            M = fmaxf(M, ml.x);
        }
        float L = 0.f, o = 0.f;
        for (int c = 0; c < NS; ++c) {
            float wgt = __expf(mv[c] - M);
            L += wgt * lv[c];
            o += wgt * pO[((size_t)(bh * NS + c) * Pp + p) * Dd + d];
        }
        out[((size_t)bh * Pp + p) * Dd + d] = o / L;
    }
}

// ---------------- launcher ----------------
extern "C" void kernel_launch(void* const* d_in, const int* in_sizes, int n_in,
                              void* d_out, int out_size, void* d_ws, size_t ws_size,
                              hipStream_t stream) {
    const float* q         = (const float*)d_in[0];
    const float* k         = (const float*)d_in[1];
    const float* v         = (const float*)d_in[2];
    const int*   regions   = (const int*)d_in[3];
    const float* bias_same = (const float*)d_in[7];
    const float* bias_diff = (const float*)d_in[8];

    float* ws     = (float*)d_ws;
    float* postab = ws;
    float* regtab = postab + Tt * 16 * 2;
    int*   starts = (int*)(regtab + 33 * 16 * 2);
    float* pbase  = (float*)(starts + 128);
    size_t fixed_b = (size_t)((char*)pbase - (char*)ws);

    int NS = 4;   // 256 blocks = exactly 1 per CU, single round
    while (NS > 1 && fixed_b + (size_t)BHc * NS * Pp * (Dd + 2) * 4 > ws_size) NS >>= 1;
    float* pO  = pbase;
    float* pML = pO + (size_t)BHc * NS * Pp * Dd;

    k_postab<<<dim3(Tt * 16 / 256), dim3(256), 0, stream>>>(postab);
    k_prep<<<dim3(1), dim3(704), 0, stream>>>(regions, regtab, starts);
    k_attn<<<dim3(BHc * NS), dim3(512), 0, stream>>>(q, k, v, regions, bias_same, bias_diff,
                                                     postab, regtab, starts, pO, pML, NS);
    k_combine<<<dim3(BHc * 4), dim3(256), 0, stream>>>(pO, pML, (float*)d_out, NS);
}